// Round 1
// baseline (325.459 us; speedup 1.0000x reference)
//
#include <hip/hip_runtime.h>

#define IN_C  128
#define OUT_C 32
#define BN_EPS 1e-5f

// ---------------- init: deg = 1.0 (self loop), zero BN sums ----------------
__global__ void init_kernel(float* __restrict__ deg, float* __restrict__ sums, int N) {
    int i = blockIdx.x * blockDim.x + threadIdx.x;
    if (i < N) deg[i] = 1.0f;
    if (blockIdx.x == 0 && threadIdx.x < 128) sums[threadIdx.x] = 0.0f;
}

// ---------------- degree: deg[col[e]] += 1 ----------------
__global__ void deg_kernel(const int* __restrict__ col, float* __restrict__ deg, int E) {
    int e = blockIdx.x * blockDim.x + threadIdx.x;
    if (e < E) atomicAdd(&deg[col[e]], 1.0f);
}

// ---------------- GEMM: g = rsqrt(deg[r]) * (x[r,:] @ W); acc = g ----------------
// 256 threads, 32 rows/block. tid/8 = local row, (tid&7)*4 = channel quad.
__global__ __launch_bounds__(256) void gemm_kernel(
    const float* __restrict__ x, const float* __restrict__ W,
    const float* __restrict__ deg,
    float* __restrict__ g, float* __restrict__ acc, int N)
{
    __shared__ float xs[32 * 132];   // padded stride 132 (=33*float4) -> no bank conflicts
    __shared__ float wl[128 * 32];   // 16 KB
    const int tid = threadIdx.x;
    const int r0  = blockIdx.x * 32;

    #pragma unroll
    for (int k = 0; k < 4; ++k) {
        int idx = tid + 256 * k;          // float4 index in [0,1024)
        int row = idx >> 5;               // 32 float4 per row
        int c4  = idx & 31;
        int rr  = r0 + row;
        float4 v = make_float4(0.f, 0.f, 0.f, 0.f);
        if (rr < N) v = reinterpret_cast<const float4*>(x)[(size_t)rr * 32 + c4];
        *reinterpret_cast<float4*>(&xs[row * 132 + c4 * 4]) = v;
    }
    #pragma unroll
    for (int k = 0; k < 4; ++k) {
        int idx = tid + 256 * k;          // [0,1024) float4 of W (128x32)
        reinterpret_cast<float4*>(wl)[idx] = reinterpret_cast<const float4*>(W)[idx];
    }
    __syncthreads();

    const int r_local = tid >> 3;
    const int c4 = (tid & 7) * 4;
    float4 sum = make_float4(0.f, 0.f, 0.f, 0.f);
    #pragma unroll 8
    for (int k = 0; k < 128; ++k) {
        float  xv = xs[r_local * 132 + k];
        float4 w4 = *reinterpret_cast<const float4*>(&wl[k * 32 + c4]);
        sum.x = fmaf(xv, w4.x, sum.x);
        sum.y = fmaf(xv, w4.y, sum.y);
        sum.z = fmaf(xv, w4.z, sum.z);
        sum.w = fmaf(xv, w4.w, sum.w);
    }
    const int r = r0 + r_local;
    if (r < N) {
        float dis = rsqrtf(deg[r]);
        sum.x *= dis; sum.y *= dis; sum.z *= dis; sum.w *= dis;
        size_t o = (size_t)r * 32 + c4;
        *reinterpret_cast<float4*>(&g[o])   = sum;
        *reinterpret_cast<float4*>(&acc[o]) = sum;   // self-loop init
    }
}

// ---------------- scatter: acc[col][c] += g[row][c], 32 lanes per edge ----------------
__global__ __launch_bounds__(256) void scatter_kernel(
    const int* __restrict__ row, const int* __restrict__ col,
    const float* __restrict__ g, float* __restrict__ acc, int E)
{
    long long idx = (long long)blockIdx.x * blockDim.x + threadIdx.x;
    int e = (int)(idx >> 5);
    int c = (int)(idx & 31);
    if (e < E) {
        int r = row[e];
        int t = col[e];
        atomicAdd(&acc[(size_t)t * 32 + c], g[(size_t)r * 32 + c]);
    }
}

// ---------------- finalize: out = dis*acc + b; BN partial sums ----------------
__global__ __launch_bounds__(256) void finalize_kernel(
    const float* __restrict__ deg, const float* __restrict__ bias,
    float* __restrict__ out, float* __restrict__ sums, int N)
{
    __shared__ float s1[256];
    __shared__ float s2[256];
    const int tid = threadIdx.x;
    const int c = tid & 31;
    const float bc = bias[c];
    float lsum = 0.f, lsq = 0.f;
    for (int r = blockIdx.x * 8 + (tid >> 5); r < N; r += gridDim.x * 8) {
        float dis = rsqrtf(deg[r]);
        size_t o = (size_t)r * 32 + c;
        float v = fmaf(dis, out[o], bc);
        out[o] = v;
        lsum += v;
        lsq = fmaf(v, v, lsq);
    }
    s1[tid] = lsum; s2[tid] = lsq;
    __syncthreads();
    if (tid < 128) { s1[tid] += s1[tid + 128]; s2[tid] += s2[tid + 128]; }
    __syncthreads();
    if (tid < 64)  { s1[tid] += s1[tid + 64];  s2[tid] += s2[tid + 64]; }
    __syncthreads();
    if (tid < 32) {
        atomicAdd(&sums[tid],      s1[tid] + s1[tid + 32]);
        atomicAdd(&sums[32 + tid], s2[tid] + s2[tid + 32]);
    }
}

// ---------------- stats: per-channel scale/shift ----------------
__global__ void stats_kernel(const float* __restrict__ sums,
                             const float* __restrict__ gamma,
                             const float* __restrict__ beta,
                             float* __restrict__ ss, int N)
{
    int c = threadIdx.x;
    if (c < 32) {
        float invN  = 1.0f / (float)N;
        float mean  = sums[c] * invN;
        float var   = sums[32 + c] * invN - mean * mean;
        float scale = gamma[c] * rsqrtf(var + BN_EPS);
        ss[c]      = scale;
        ss[32 + c] = fmaf(-mean, scale, beta[c]);
    }
}

// ---------------- apply BN affine in place ----------------
__global__ __launch_bounds__(256) void bn_apply_kernel(
    float* __restrict__ out, const float* __restrict__ ss, long long n4)
{
    long long i = (long long)blockIdx.x * blockDim.x + threadIdx.x;
    if (i < n4) {
        int c4 = (int)(i & 7) * 4;
        float4 v = reinterpret_cast<float4*>(out)[i];
        v.x = fmaf(v.x, ss[c4 + 0], ss[32 + c4 + 0]);
        v.y = fmaf(v.y, ss[c4 + 1], ss[32 + c4 + 1]);
        v.z = fmaf(v.z, ss[c4 + 2], ss[32 + c4 + 2]);
        v.w = fmaf(v.w, ss[c4 + 3], ss[32 + c4 + 3]);
        reinterpret_cast<float4*>(out)[i] = v;
    }
}

extern "C" void kernel_launch(void* const* d_in, const int* in_sizes, int n_in,
                              void* d_out, int out_size, void* d_ws, size_t ws_size,
                              hipStream_t stream)
{
    const float* x     = (const float*)d_in[0];
    const int*   ei    = (const int*)d_in[1];     // int32 per harness convention
    const float* W     = (const float*)d_in[2];
    const float* b     = (const float*)d_in[3];
    const float* gamma = (const float*)d_in[4];
    const float* beta  = (const float*)d_in[5];
    float* out = (float*)d_out;

    const int N = in_sizes[0] / IN_C;
    const int E = in_sizes[1] / 2;
    const int* row = ei;          // edge_index[0] = sources
    const int* col = ei + E;      // edge_index[1] = targets

    // workspace layout: g[N*32] | deg[N] | sums[128] (sum, sumsq, scale, shift)
    float* g    = (float*)d_ws;
    float* deg  = g + (size_t)N * OUT_C;
    float* sums = deg + N;

    init_kernel<<<(N + 255) / 256, 256, 0, stream>>>(deg, sums, N);
    deg_kernel<<<(E + 255) / 256, 256, 0, stream>>>(col, deg, E);
    gemm_kernel<<<(N + 31) / 32, 256, 0, stream>>>(x, W, deg, g, out, N);

    long long total = (long long)E * 32;
    scatter_kernel<<<(int)((total + 255) / 256), 256, 0, stream>>>(row, col, g, out, E);

    finalize_kernel<<<2048, 256, 0, stream>>>(deg, b, out, sums, N);
    stats_kernel<<<1, 64, 0, stream>>>(sums, gamma, beta, sums + 64, N);

    long long n4 = (long long)N * OUT_C / 4;
    bn_apply_kernel<<<(int)((n4 + 255) / 256), 256, 0, stream>>>(out, sums + 64, n4);
}

// Round 2
// 323.139 us; speedup vs baseline: 1.0072x; 1.0072x over previous
//
#include <hip/hip_runtime.h>

#define IN_C  128
#define OUT_C 32
#define BN_EPS 1e-5f

// ---------------- zero: counts = 0, BN sums = 0 ----------------
__global__ void zero_kernel(int* __restrict__ counts, float* __restrict__ sums, int N) {
    int i = blockIdx.x * blockDim.x + threadIdx.x;
    if (i < N) counts[i] = 0;
    if (blockIdx.x == 0 && threadIdx.x < 128) sums[threadIdx.x] = 0.0f;
}

// ---------------- histogram of targets: counts[col[e]]++ ----------------
__global__ void hist_kernel(const int* __restrict__ col, int* __restrict__ counts, int E) {
    int e = blockIdx.x * blockDim.x + threadIdx.x;
    if (e < E) atomicAdd(&counts[col[e]], 1);
}

// ---------------- scan pass A: per-block (1024 elems) sums ----------------
__global__ __launch_bounds__(256) void scanA_kernel(const int* __restrict__ counts,
                                                    int* __restrict__ bsum, int N) {
    __shared__ int sd[256];
    int t = threadIdx.x;
    int base = blockIdx.x * 1024 + t * 4;
    int s = 0;
    if (base + 3 < N) {
        int4 v = *reinterpret_cast<const int4*>(&counts[base]);
        s = v.x + v.y + v.z + v.w;
    } else {
        for (int j = 0; j < 4; ++j) if (base + j < N) s += counts[base + j];
    }
    sd[t] = s; __syncthreads();
    for (int off = 128; off > 0; off >>= 1) {
        if (t < off) sd[t] += sd[t + off];
        __syncthreads();
    }
    if (t == 0) bsum[blockIdx.x] = sd[0];
}

// ---------------- scan pass B: exclusive scan of block sums (tiny) ----------------
__global__ void scanB_kernel(int* __restrict__ bsum, int nb) {
    if (threadIdx.x == 0 && blockIdx.x == 0) {
        int run = 0;
        for (int i = 0; i < nb; ++i) { int v = bsum[i]; bsum[i] = run; run += v; }
    }
}

// ---------------- scan pass C: per-element exclusive offsets + cursor copy ----------------
__global__ __launch_bounds__(256) void scanC_kernel(const int* __restrict__ counts,
                                                    const int* __restrict__ bsum,
                                                    int* __restrict__ offs,
                                                    int* __restrict__ cursor, int N) {
    __shared__ int sd[256];
    int t = threadIdx.x;
    int base = blockIdx.x * 1024 + t * 4;
    int c0 = 0, c1 = 0, c2 = 0, c3 = 0;
    if (base + 3 < N) {
        int4 v = *reinterpret_cast<const int4*>(&counts[base]);
        c0 = v.x; c1 = v.y; c2 = v.z; c3 = v.w;
    } else {
        if (base     < N) c0 = counts[base];
        if (base + 1 < N) c1 = counts[base + 1];
        if (base + 2 < N) c2 = counts[base + 2];
        if (base + 3 < N) c3 = counts[base + 3];
    }
    int s = c0 + c1 + c2 + c3;
    sd[t] = s; __syncthreads();
    // Hillis-Steele inclusive scan of thread sums
    for (int off = 1; off < 256; off <<= 1) {
        int v = (t >= off) ? sd[t - off] : 0;
        __syncthreads();
        sd[t] += v;
        __syncthreads();
    }
    int pre = sd[t] - s + bsum[blockIdx.x];   // exclusive base for this thread
    int o0 = pre, o1 = o0 + c0, o2 = o1 + c1, o3 = o2 + c2;
    if (base + 3 < N) {
        *reinterpret_cast<int4*>(&offs[base])   = make_int4(o0, o1, o2, o3);
        *reinterpret_cast<int4*>(&cursor[base]) = make_int4(o0, o1, o2, o3);
    } else {
        if (base     < N) { offs[base]     = o0; cursor[base]     = o0; }
        if (base + 1 < N) { offs[base + 1] = o1; cursor[base + 1] = o1; }
        if (base + 2 < N) { offs[base + 2] = o2; cursor[base + 2] = o2; }
        if (base + 3 < N) { offs[base + 3] = o3; cursor[base + 3] = o3; }
    }
}

// ---------------- CSR fill: adj[cursor[col[e]]++] = row[e] ----------------
__global__ void fill_kernel(const int* __restrict__ row, const int* __restrict__ col,
                            int* __restrict__ cursor, int* __restrict__ adj, int E) {
    int e = blockIdx.x * blockDim.x + threadIdx.x;
    if (e < E) {
        int t = col[e];
        int p = atomicAdd(&cursor[t], 1);
        adj[p] = row[e];
    }
}

// ---------------- GEMM: g = rsqrt(deg) * (x @ W), deg = counts + 1 ----------------
__global__ __launch_bounds__(256) void gemm_kernel(
    const float* __restrict__ x, const float* __restrict__ W,
    const int* __restrict__ counts, float* __restrict__ g, int N)
{
    __shared__ float xs[32 * 132];
    __shared__ float wl[128 * 32];
    const int tid = threadIdx.x;
    const int r0  = blockIdx.x * 32;

    #pragma unroll
    for (int k = 0; k < 4; ++k) {
        int idx = tid + 256 * k;
        int row = idx >> 5;
        int c4  = idx & 31;
        int rr  = r0 + row;
        float4 v = make_float4(0.f, 0.f, 0.f, 0.f);
        if (rr < N) v = reinterpret_cast<const float4*>(x)[(size_t)rr * 32 + c4];
        *reinterpret_cast<float4*>(&xs[row * 132 + c4 * 4]) = v;
    }
    #pragma unroll
    for (int k = 0; k < 4; ++k) {
        int idx = tid + 256 * k;
        reinterpret_cast<float4*>(wl)[idx] = reinterpret_cast<const float4*>(W)[idx];
    }
    __syncthreads();

    const int r_local = tid >> 3;
    const int c4 = (tid & 7) * 4;
    float4 sum = make_float4(0.f, 0.f, 0.f, 0.f);
    #pragma unroll 8
    for (int k = 0; k < 128; ++k) {
        float  xv = xs[r_local * 132 + k];
        float4 w4 = *reinterpret_cast<const float4*>(&wl[k * 32 + c4]);
        sum.x = fmaf(xv, w4.x, sum.x);
        sum.y = fmaf(xv, w4.y, sum.y);
        sum.z = fmaf(xv, w4.z, sum.z);
        sum.w = fmaf(xv, w4.w, sum.w);
    }
    const int r = r0 + r_local;
    if (r < N) {
        float dis = rsqrtf((float)counts[r] + 1.0f);
        sum.x *= dis; sum.y *= dis; sum.z *= dis; sum.w *= dis;
        *reinterpret_cast<float4*>(&g[(size_t)r * 32 + c4]) = sum;
    }
}

// ---------------- pull: out[i] = d_i*(g_i + sum_adj g) + b; BN partial sums ----------------
__global__ __launch_bounds__(256) void pull_kernel(
    const int* __restrict__ counts, const int* __restrict__ offs,
    const int* __restrict__ adj, const float* __restrict__ g,
    const float* __restrict__ bias, float* __restrict__ out,
    float* __restrict__ sums, int N)
{
    __shared__ float s1[256];
    __shared__ float s2[256];
    const int tid = threadIdx.x;
    const int c = tid & 31;
    const float bc = bias[c];
    float lsum = 0.f, lsq = 0.f;

    for (int i = blockIdx.x * 8 + (tid >> 5); i < N; i += gridDim.x * 8) {
        const int start = offs[i];
        const int len   = counts[i];
        float acc = g[(size_t)i * 32 + c];          // self-loop term
        int k = 0;
        for (; k + 4 <= len; k += 4) {
            int r0 = adj[start + k];
            int r1 = adj[start + k + 1];
            int r2 = adj[start + k + 2];
            int r3 = adj[start + k + 3];
            float v0 = g[(size_t)r0 * 32 + c];
            float v1 = g[(size_t)r1 * 32 + c];
            float v2 = g[(size_t)r2 * 32 + c];
            float v3 = g[(size_t)r3 * 32 + c];
            acc += (v0 + v1) + (v2 + v3);
        }
        for (; k < len; ++k) acc += g[(size_t)adj[start + k] * 32 + c];

        float dis = rsqrtf((float)len + 1.0f);
        float v = fmaf(dis, acc, bc);
        out[(size_t)i * 32 + c] = v;
        lsum += v;
        lsq = fmaf(v, v, lsq);
    }

    s1[tid] = lsum; s2[tid] = lsq;
    __syncthreads();
    if (tid < 128) { s1[tid] += s1[tid + 128]; s2[tid] += s2[tid + 128]; }
    __syncthreads();
    if (tid < 64)  { s1[tid] += s1[tid + 64];  s2[tid] += s2[tid + 64]; }
    __syncthreads();
    if (tid < 32) {
        atomicAdd(&sums[tid],      s1[tid] + s1[tid + 32]);
        atomicAdd(&sums[32 + tid], s2[tid] + s2[tid + 32]);
    }
}

// ---------------- stats: per-channel scale/shift ----------------
__global__ void stats_kernel(const float* __restrict__ sums,
                             const float* __restrict__ gamma,
                             const float* __restrict__ beta,
                             float* __restrict__ ss, int N)
{
    int c = threadIdx.x;
    if (c < 32) {
        float invN  = 1.0f / (float)N;
        float mean  = sums[c] * invN;
        float var   = sums[32 + c] * invN - mean * mean;
        float scale = gamma[c] * rsqrtf(var + BN_EPS);
        ss[c]      = scale;
        ss[32 + c] = fmaf(-mean, scale, beta[c]);
    }
}

// ---------------- apply BN affine in place ----------------
__global__ __launch_bounds__(256) void bn_apply_kernel(
    float* __restrict__ out, const float* __restrict__ ss, long long n4)
{
    long long i = (long long)blockIdx.x * blockDim.x + threadIdx.x;
    if (i < n4) {
        int c4 = (int)(i & 7) * 4;
        float4 v = reinterpret_cast<float4*>(out)[i];
        v.x = fmaf(v.x, ss[c4 + 0], ss[32 + c4 + 0]);
        v.y = fmaf(v.y, ss[c4 + 1], ss[32 + c4 + 1]);
        v.z = fmaf(v.z, ss[c4 + 2], ss[32 + c4 + 2]);
        v.w = fmaf(v.w, ss[c4 + 3], ss[32 + c4 + 3]);
        reinterpret_cast<float4*>(out)[i] = v;
    }
}

extern "C" void kernel_launch(void* const* d_in, const int* in_sizes, int n_in,
                              void* d_out, int out_size, void* d_ws, size_t ws_size,
                              hipStream_t stream)
{
    const float* x     = (const float*)d_in[0];
    const int*   ei    = (const int*)d_in[1];
    const float* W     = (const float*)d_in[2];
    const float* b     = (const float*)d_in[3];
    const float* gamma = (const float*)d_in[4];
    const float* beta  = (const float*)d_in[5];
    float* out = (float*)d_out;

    const int N = in_sizes[0] / IN_C;
    const int E = in_sizes[1] / 2;
    const int* row = ei;          // sources
    const int* col = ei + E;      // targets

    // workspace: g[N*32] f32 | sums[192] f32 | counts[N] | offs[N] | cursor[N] | bsum[128] | adj[E]
    float* g      = (float*)d_ws;
    float* sums   = g + (size_t)N * OUT_C;          // 0..31 sum, 32..63 sumsq, 64..127 scale/shift
    int*   counts = (int*)(sums + 192);
    int*   offs   = counts + N;
    int*   cursor = offs + N;
    int*   bsum   = cursor + N;
    int*   adj    = bsum + 128;

    const int NB = (N + 1023) / 1024;               // scan blocks (98 for N=100000)

    zero_kernel <<<(N + 255) / 256, 256, 0, stream>>>(counts, sums, N);
    hist_kernel <<<(E + 255) / 256, 256, 0, stream>>>(col, counts, E);
    scanA_kernel<<<NB, 256, 0, stream>>>(counts, bsum, N);
    scanB_kernel<<<1, 64, 0, stream>>>(bsum, NB);
    scanC_kernel<<<NB, 256, 0, stream>>>(counts, bsum, offs, cursor, N);
    fill_kernel <<<(E + 255) / 256, 256, 0, stream>>>(row, col, cursor, adj, E);

    gemm_kernel <<<(N + 31) / 32, 256, 0, stream>>>(x, W, counts, g, N);
    pull_kernel <<<2048, 256, 0, stream>>>(counts, offs, adj, g, b, out, sums, N);

    stats_kernel<<<1, 64, 0, stream>>>(sums, gamma, beta, sums + 64, N);

    long long n4 = (long long)N * OUT_C / 4;
    bn_apply_kernel<<<(int)((n4 + 255) / 256), 256, 0, stream>>>(out, sums + 64, n4);
}